// Round 2
// baseline (233.750 us; speedup 1.0000x reference)
//
#include <hip/hip_runtime.h>

typedef unsigned int u32;

#define NB 256      // batches
#define NNODE 256   // nodes (== NB, required by mask broadcast)
#define FF 128      // in features
#define NH 4        // heads
#define DD 8        // per-head dim
#define HDIM 32     // NH*DD
#define NCOLS 96    // 3*HDIM (q|k|v)
#define NROWS (NB*NNODE)

// ---------------- prep: adjacency bitmask + transposed weights ----------------
__global__ __launch_bounds__(256) void prep_kernel(
    const int* __restrict__ eidx, int E,
    const float* __restrict__ Wq, const float* __restrict__ bq,
    const float* __restrict__ Wk, const float* __restrict__ bk,
    const float* __restrict__ Wv, const float* __restrict__ bv,
    u32* __restrict__ mask, float* __restrict__ Wt, float* __restrict__ bias)
{
  int t = threadIdx.x;
  for (int i = t; i < NNODE*8; i += 256) mask[i] = 0u;
  // Wt[c][f] = W_mat(c)[f][c%32]  (c: 0..31 q, 32..63 k, 64..95 v)
  for (int i = t; i < NCOLS*FF; i += 256) {
    int c = i / FF, f = i % FF;
    const float* W = (c < 32) ? Wq : ((c < 64) ? Wk : Wv);
    Wt[i] = W[f*HDIM + (c & 31)];
  }
  for (int i = t; i < NCOLS; i += 256) {
    const float* bb = (i < 32) ? bq : ((i < 64) ? bk : bv);
    bias[i] = bb[i & 31];
  }
  __syncthreads();
  for (int e = t; e < E; e += 256) {
    int r = eidx[e];
    int c = eidx[E + e];
    atomicOr(&mask[r*8 + (c >> 5)], 1u << (c & 31));
  }
}

// ---------------- QKV projection: x[65536,128] @ Wt^T -> q,k,v [65536,32] f32 -----
__global__ __launch_bounds__(256) void qkv_kernel(
    const float* __restrict__ x, const float* __restrict__ Wt,
    const float* __restrict__ bias,
    float* __restrict__ qb, float* __restrict__ kb, float* __restrict__ vb)
{
  int t = threadIdx.x;
  int tr = t >> 4;          // 0..15 -> 4 rows each
  int tc = t & 15;          // 0..15 -> 6 cols each
  int row0 = blockIdx.x * 64 + tr * 4;
  int c0 = tc * 6;
  float acc[4][6];
  #pragma unroll
  for (int i = 0; i < 4; ++i)
    #pragma unroll
    for (int j = 0; j < 6; ++j) acc[i][j] = 0.f;

  for (int f = 0; f < FF; f += 8) {
    float xv[4][8];
    #pragma unroll
    for (int i = 0; i < 4; ++i) {
      const float* xp = x + (size_t)(row0 + i)*FF + f;
      float4 a = *(const float4*)(xp);
      float4 b = *(const float4*)(xp + 4);
      xv[i][0]=a.x; xv[i][1]=a.y; xv[i][2]=a.z; xv[i][3]=a.w;
      xv[i][4]=b.x; xv[i][5]=b.y; xv[i][6]=b.z; xv[i][7]=b.w;
    }
    #pragma unroll
    for (int j = 0; j < 6; ++j) {
      const float* wp = Wt + (size_t)(c0 + j)*FF + f;
      float4 w0 = *(const float4*)(wp);
      float4 w1 = *(const float4*)(wp + 4);
      #pragma unroll
      for (int i = 0; i < 4; ++i) {
        acc[i][j] += xv[i][0]*w0.x + xv[i][1]*w0.y + xv[i][2]*w0.z + xv[i][3]*w0.w
                   + xv[i][4]*w1.x + xv[i][5]*w1.y + xv[i][6]*w1.z + xv[i][7]*w1.w;
      }
    }
  }
  #pragma unroll
  for (int j = 0; j < 6; ++j) {
    int c = c0 + j;
    float bb = bias[c];
    float* dst = (c < 32) ? qb : ((c < 64) ? kb : vb);
    int cc = c & 31;
    #pragma unroll
    for (int i = 0; i < 4; ++i) {
      dst[(size_t)(row0 + i)*HDIM + cc] = acc[i][j] + bb;
    }
  }
}

// ---------------- attention: one wave per (b,h), 4 q-rows per lane ----------------
__global__ __launch_bounds__(64) void attn_kernel(
    const float* __restrict__ qb, const float* __restrict__ kb,
    const float* __restrict__ vb, const u32* __restrict__ mask,
    float* __restrict__ ob)
{
  __shared__ float kS[NNODE][8];
  __shared__ float vS[NNODE][8];
  __shared__ u32 mS[NNODE*8];
  int lane = threadIdx.x;
  int b = blockIdx.x >> 2;
  int h = blockIdx.x & 3;
  size_t base = ((size_t)b*NNODE)*HDIM + h*DD;

  for (int r = lane; r < NNODE; r += 64) {
    const float4* ks = (const float4*)(kb + base + (size_t)r*HDIM);
    ((float4*)(&kS[r][0]))[0] = ks[0];
    ((float4*)(&kS[r][0]))[1] = ks[1];
    const float4* vs = (const float4*)(vb + base + (size_t)r*HDIM);
    ((float4*)(&vS[r][0]))[0] = vs[0];
    ((float4*)(&vS[r][0]))[1] = vs[1];
  }
  for (int i = lane; i < NNODE*8; i += 64) mS[i] = mask[i];
  __syncthreads();

  const float sc = 0.3535533905932738f;  // 1/sqrt(8)
  float qv[4][8], l[4], M[4], acc[4][8];
  #pragma unroll
  for (int j = 0; j < 4; ++j) {
    int qi = lane + j*64;
    const float4* qs = (const float4*)(qb + base + (size_t)qi*HDIM);
    float4 a = qs[0], c4 = qs[1];
    qv[j][0]=a.x*sc;  qv[j][1]=a.y*sc;  qv[j][2]=a.z*sc;  qv[j][3]=a.w*sc;
    qv[j][4]=c4.x*sc; qv[j][5]=c4.y*sc; qv[j][6]=c4.z*sc; qv[j][7]=c4.w*sc;
    l[j] = 0.f; M[j] = 0.f;
    #pragma unroll
    for (int d = 0; d < 8; ++d) acc[j][d] = 0.f;
  }

  for (int w = 0; w < 8; ++w) {
    u32 mw[4];
    #pragma unroll
    for (int j = 0; j < 4; ++j) mw[j] = mS[(lane + j*64)*8 + w];
    #pragma unroll 4
    for (int kk = 0; kk < 32; ++kk) {
      int nk = w*32 + kk;
      float4 k0 = ((const float4*)(&kS[nk][0]))[0];
      float4 k1 = ((const float4*)(&kS[nk][0]))[1];
      float4 v0 = ((const float4*)(&vS[nk][0]))[0];
      float4 v1 = ((const float4*)(&vS[nk][0]))[1];
      #pragma unroll
      for (int j = 0; j < 4; ++j) {
        float s = qv[j][0]*k0.x + qv[j][1]*k0.y + qv[j][2]*k0.z + qv[j][3]*k0.w
                + qv[j][4]*k1.x + qv[j][5]*k1.y + qv[j][6]*k1.z + qv[j][7]*k1.w;
        s = ((mw[j] >> kk) & 1u) ? s : -1e30f;
        // deferred-max online softmax: anchor M=0, rescale only if p would overflow
        if (__builtin_expect(s > M[j] + 8.f, 0)) {
          float c = __expf(M[j] - s);
          M[j] = s; l[j] *= c;
          #pragma unroll
          for (int d = 0; d < 8; ++d) acc[j][d] *= c;
        }
        float p = __expf(s - M[j]);   // masked: exp(-1e30 - M) == 0
        l[j] += p;
        acc[j][0] += p*v0.x; acc[j][1] += p*v0.y; acc[j][2] += p*v0.z; acc[j][3] += p*v0.w;
        acc[j][4] += p*v1.x; acc[j][5] += p*v1.y; acc[j][6] += p*v1.z; acc[j][7] += p*v1.w;
      }
    }
  }
  #pragma unroll
  for (int j = 0; j < 4; ++j) {
    int qi = lane + j*64;
    float inv = 1.f / l[j];
    float* dst = ob + ((size_t)b*NNODE + qi)*HDIM + h*DD;
    float4 o0, o1;
    o0.x=acc[j][0]*inv; o0.y=acc[j][1]*inv; o0.z=acc[j][2]*inv; o0.w=acc[j][3]*inv;
    o1.x=acc[j][4]*inv; o1.y=acc[j][5]*inv; o1.z=acc[j][6]*inv; o1.w=acc[j][7]*inv;
    ((float4*)dst)[0] = o0;
    ((float4*)dst)[1] = o1;
  }
}

// ---------------- output projection: o[65536,32] @ Wo[32,8] + bo -> f32 ----------
__global__ __launch_bounds__(256) void proj_kernel(
    const float* __restrict__ ob, const float* __restrict__ Wo,
    const float* __restrict__ bo, float* __restrict__ out)
{
  __shared__ float woS[HDIM*DD];
  __shared__ float boS[DD];
  int t = threadIdx.x;
  if (t < HDIM*DD) woS[t] = Wo[t];
  if (t < DD) boS[t] = bo[t];
  __syncthreads();
  size_t row = (size_t)blockIdx.x * 256 + t;
  const float4* o4 = (const float4*)(ob + row*HDIM);
  float ov[32];
  #pragma unroll
  for (int i = 0; i < 8; ++i) {
    float4 o = o4[i];
    ov[i*4+0]=o.x; ov[i*4+1]=o.y; ov[i*4+2]=o.z; ov[i*4+3]=o.w;
  }
  float r[8];
  #pragma unroll
  for (int d = 0; d < 8; ++d) r[d] = boS[d];
  #pragma unroll
  for (int hd = 0; hd < 32; ++hd) {
    float o = ov[hd];
    #pragma unroll
    for (int d = 0; d < 8; ++d) r[d] += o * woS[hd*8 + d];
  }
  float* dst = out + row*DD;
  float4 r0, r1;
  r0.x=r[0]; r0.y=r[1]; r0.z=r[2]; r0.w=r[3];
  r1.x=r[4]; r1.y=r[5]; r1.z=r[6]; r1.w=r[7];
  ((float4*)dst)[0] = r0;
  ((float4*)dst)[1] = r1;
}

extern "C" void kernel_launch(void* const* d_in, const int* in_sizes, int n_in,
                              void* d_out, int out_size, void* d_ws, size_t ws_size,
                              hipStream_t stream)
{
  const float* x  = (const float*)d_in[0];
  const int*   ei = (const int*)d_in[1];
  const float* Wq = (const float*)d_in[2];
  const float* bq = (const float*)d_in[3];
  const float* Wk = (const float*)d_in[4];
  const float* bk = (const float*)d_in[5];
  const float* Wv = (const float*)d_in[6];
  const float* bv = (const float*)d_in[7];
  const float* Wo = (const float*)d_in[8];
  const float* bo = (const float*)d_in[9];
  int E = in_sizes[1] / 2;

  char* ws = (char*)d_ws;
  u32*   mask = (u32*)(ws + 0);                        // 8 KB
  float* Wt   = (float*)(ws + 8192);                   // 48 KB
  float* bias = (float*)(ws + 8192 + 49152);           // 384 B
  float* qb   = (float*)(ws + 65536);                  // 8 MB each
  float* kb   = qb + (size_t)NROWS*HDIM;
  float* vb   = kb + (size_t)NROWS*HDIM;
  float* obuf = vb + (size_t)NROWS*HDIM;

  prep_kernel<<<1, 256, 0, stream>>>(ei, E, Wq, bq, Wk, bk, Wv, bv, mask, Wt, bias);
  qkv_kernel<<<NROWS/64, 256, 0, stream>>>(x, Wt, bias, qb, kb, vb);
  attn_kernel<<<NB*NH, 64, 0, stream>>>(qb, kb, vb, mask, obuf);
  proj_kernel<<<NB, 256, 0, stream>>>(obuf, Wo, bo, (float*)d_out);
}

// Round 4
// 91.382 us; speedup vs baseline: 2.5579x; 2.5579x over previous
//
#include <hip/hip_runtime.h>

typedef unsigned int u32;
typedef __fp16 h2 __attribute__((ext_vector_type(2)));

#define NB 256      // batches
#define NNODE 256   // nodes
#define FF 128      // in features
#define NH 4        // heads
#define DD 8        // per-head dim
#define HDIM 32     // NH*DD
#define NCOLS 96    // 3*HDIM
#define NROWS (NB*NNODE)

__device__ __forceinline__ float dot2(h2 a, h2 b, float c) {
#if __has_builtin(__builtin_amdgcn_fdot2)
  return __builtin_amdgcn_fdot2(a, b, c, false);
#else
  return c + (float)a.x * (float)b.x + (float)a.y * (float)b.y;
#endif
}
__device__ __forceinline__ h2 bch2(u32 u) { return __builtin_bit_cast(h2, u); }

// ---------------- prep_w: zero mask, pack W -> f16 pairs (transposed), bias -----
__global__ __launch_bounds__(256) void prep_w_kernel(
    const float* __restrict__ Wq, const float* __restrict__ bq,
    const float* __restrict__ Wk, const float* __restrict__ bk,
    const float* __restrict__ Wv, const float* __restrict__ bv,
    u32* __restrict__ mask, u32* __restrict__ WtH, float* __restrict__ bias)
{
  int g = blockIdx.x * 256 + threadIdx.x;
  if (g < NCOLS * 64) {              // WtH[c][fp]: pack W[2fp][c], W[2fp+1][c]
    int c = g >> 6, f = (g & 63) * 2;
    const float* W = (c < 32) ? Wq : ((c < 64) ? Wk : Wv);
    int cc = c & 31;
    h2 p = __builtin_amdgcn_cvt_pkrtz(W[f*HDIM + cc], W[(f+1)*HDIM + cc]);
    WtH[g] = __builtin_bit_cast(u32, p);
  }
  if (g < NNODE * 8) mask[g] = 0u;
  if (g < NCOLS) {
    const float* bb = (g < 32) ? bq : ((g < 64) ? bk : bv);
    bias[g] = bb[g & 31];
  }
}

// ---------------- prep_e: scatter edges into bitmask ---------------------------
__global__ __launch_bounds__(256) void prep_e_kernel(
    const int* __restrict__ eidx, int E, u32* __restrict__ mask)
{
  int e = blockIdx.x * 256 + threadIdx.x;
  if (e < E) {
    int r = eidx[e], c = eidx[E + e];
    atomicOr(&mask[r*8 + (c >> 5)], 1u << (c & 31));
  }
}

// ---------------- QKV: x[65536,128] @ W -> q,k,v f16 [65536,32] -----------------
// block: 256 thr, 64 rows; thread: 2 rows x 12 cols; W f16 in LDS (XOR-swizzled)
__device__ __forceinline__ void qkv_step(float (&acc)[2][12], const float4 (&xr)[2][2],
                                         const u32* wS, int tc, int fp)
{
  h2 xk[2][4];
  #pragma unroll
  for (int i = 0; i < 2; ++i) {
    xk[i][0] = __builtin_amdgcn_cvt_pkrtz(xr[i][0].x, xr[i][0].y);
    xk[i][1] = __builtin_amdgcn_cvt_pkrtz(xr[i][0].z, xr[i][0].w);
    xk[i][2] = __builtin_amdgcn_cvt_pkrtz(xr[i][1].x, xr[i][1].y);
    xk[i][3] = __builtin_amdgcn_cvt_pkrtz(xr[i][1].z, xr[i][1].w);
  }
  #pragma unroll
  for (int j = 0; j < 12; ++j) {
    int c = tc + 8*j;
    uint4 w4 = *(const uint4*)&wS[c*64 + (fp ^ (4*(c & 7)))];
    h2 w0 = bch2(w4.x), w1 = bch2(w4.y), w2 = bch2(w4.z), w3 = bch2(w4.w);
    #pragma unroll
    for (int i = 0; i < 2; ++i)
      acc[i][j] = dot2(xk[i][3], w3, dot2(xk[i][2], w2,
                  dot2(xk[i][1], w1, dot2(xk[i][0], w0, acc[i][j]))));
  }
}

__global__ __launch_bounds__(256, 4) void qkv_kernel(
    const float* __restrict__ x, const u32* __restrict__ WtH,
    const float* __restrict__ bias,
    __fp16* __restrict__ qh, __fp16* __restrict__ kh, __fp16* __restrict__ vh)
{
  __shared__ u32 wS[NCOLS * 64];     // 24 KB, f16-packed, XOR-swizzled
  int t = threadIdx.x;
  #pragma unroll
  for (int i0 = 0; i0 < NCOLS*64; i0 += 256) {
    int g = i0 + t;
    int c = g >> 6, fp = g & 63;
    wS[c*64 + (fp ^ (4*(c & 7)))] = WtH[g];
  }
  __syncthreads();

  int tr = t >> 3, tc = t & 7;               // 32 row-groups x 8 col-groups
  int row0 = blockIdx.x * 64 + tr * 2;
  const float* xp = x + (size_t)row0 * FF;

  float acc[2][12];
  #pragma unroll
  for (int i = 0; i < 2; ++i)
    #pragma unroll
    for (int j = 0; j < 12; ++j) acc[i][j] = 0.f;

  float4 xa[2][2], xb[2][2];
  #pragma unroll
  for (int i = 0; i < 2; ++i) {
    xa[i][0] = *(const float4*)(xp + i*FF);
    xa[i][1] = *(const float4*)(xp + i*FF + 4);
  }
  for (int f = 0; f < FF; f += 16) {
    #pragma unroll
    for (int i = 0; i < 2; ++i) {
      xb[i][0] = *(const float4*)(xp + i*FF + f + 8);
      xb[i][1] = *(const float4*)(xp + i*FF + f + 12);
    }
    qkv_step(acc, xa, wS, tc, f >> 1);
    if (f + 16 < FF) {
      #pragma unroll
      for (int i = 0; i < 2; ++i) {
        xa[i][0] = *(const float4*)(xp + i*FF + f + 16);
        xa[i][1] = *(const float4*)(xp + i*FF + f + 20);
      }
    }
    qkv_step(acc, xb, wS, tc, (f >> 1) + 4);
  }
  #pragma unroll
  for (int j = 0; j < 12; ++j) {
    int c = tc + 8*j;
    float bb = bias[c];
    __fp16* dst = (j < 4) ? qh : ((j < 8) ? kh : vh);
    int cc = tc + 8*(j & 3);
    #pragma unroll
    for (int i = 0; i < 2; ++i)
      dst[(size_t)(row0 + i)*HDIM + cc] = (__fp16)(acc[i][j] + bb);
  }
}

// ---------------- attention: 4 waves/block, 1 q-row per lane --------------------
__global__ __launch_bounds__(256) void attn_kernel(
    const u32* __restrict__ qH, const u32* __restrict__ kH,
    const u32* __restrict__ vH, const u32* __restrict__ mask,
    float* __restrict__ ob)
{
  __shared__ u32 kS[NNODE * 4];      // f16-packed k rows (head slice), 4 KB
  __shared__ float vS[NNODE * 8];    // f32 v rows, 8 KB
  int t = threadIdx.x;
  int b = blockIdx.x >> 2, h = blockIdx.x & 3;
  size_t rbase = (size_t)b * NNODE * 16 + h * 4;   // u32 units; row stride 16

  uint4 kr = *(const uint4*)(kH + rbase + (size_t)t * 16);
  *(uint4*)&kS[t * 4] = kr;
  uint4 vr = *(const uint4*)(vH + rbase + (size_t)t * 16);
  {
    h2 a = bch2(vr.x), c = bch2(vr.y), d = bch2(vr.z), e = bch2(vr.w);
    float4 f0 = { (float)a.x, (float)a.y, (float)c.x, (float)c.y };
    float4 f1 = { (float)d.x, (float)d.y, (float)e.x, (float)e.y };
    *(float4*)&vS[t * 8]     = f0;
    *(float4*)&vS[t * 8 + 4] = f1;
  }
  uint4 mq0 = *(const uint4*)(mask + t * 8);
  uint4 mq1 = *(const uint4*)(mask + t * 8 + 4);
  u32 mr[8] = { mq0.x, mq0.y, mq0.z, mq0.w, mq1.x, mq1.y, mq1.z, mq1.w };
  uint4 qr = *(const uint4*)(qH + rbase + (size_t)t * 16);
  h2 q0 = bch2(qr.x), q1 = bch2(qr.y), q2 = bch2(qr.z), q3 = bch2(qr.w);

  float l = 0.f, M = 0.f, acc[8];
  #pragma unroll
  for (int d = 0; d < 8; ++d) acc[d] = 0.f;
  __syncthreads();

  const float sc2 = 0.3535533905932738f * 1.44269504088896f;  // 1/sqrt(8)*log2(e)
  #pragma unroll
  for (int w8 = 0; w8 < 8; ++w8) {
    u32 mw = mr[w8];
    #pragma unroll 4
    for (int kk = 0; kk < 32; ++kk) {
      int k = w8 * 32 + kk;
      uint4 kw = *(const uint4*)&kS[k * 4];
      float s = dot2(q3, bch2(kw.w), dot2(q2, bch2(kw.z),
                dot2(q1, bch2(kw.y), dot2(q0, bch2(kw.x), 0.f))));
      float4 vv0 = *(const float4*)&vS[k * 8];
      float4 vv1 = *(const float4*)&vS[k * 8 + 4];
      float e = __builtin_fmaf(s, sc2, -M);    // log2-domain score minus anchor
      e = ((mw >> kk) & 1u) ? e : -1e30f;
      if (__builtin_expect(e > 11.5f, 0)) {    // deferred-max rescale (rare)
        float cf = exp2f(-e);
        M += e; l *= cf;
        #pragma unroll
        for (int d = 0; d < 8; ++d) acc[d] *= cf;
        e = 0.f;
      }
      float p = exp2f(e);
      l += p;
      acc[0] += p*vv0.x; acc[1] += p*vv0.y; acc[2] += p*vv0.z; acc[3] += p*vv0.w;
      acc[4] += p*vv1.x; acc[5] += p*vv1.y; acc[6] += p*vv1.z; acc[7] += p*vv1.w;
    }
  }
  float inv = 1.f / l;
  float* dst = ob + ((size_t)b * NNODE + t) * HDIM + h * DD;
  float4 o0 = { acc[0]*inv, acc[1]*inv, acc[2]*inv, acc[3]*inv };
  float4 o1 = { acc[4]*inv, acc[5]*inv, acc[6]*inv, acc[7]*inv };
  ((float4*)dst)[0] = o0;
  ((float4*)dst)[1] = o1;
}

// ---------------- output projection: o[65536,32] @ Wo[32,8] + bo ----------------
__global__ __launch_bounds__(256) void proj_kernel(
    const float* __restrict__ ob, const float* __restrict__ Wo,
    const float* __restrict__ bo, float* __restrict__ out)
{
  __shared__ float woS[HDIM * DD];
  __shared__ float boS[DD];
  int t = threadIdx.x;
  if (t < HDIM * DD) woS[t] = Wo[t];
  if (t < DD) boS[t] = bo[t];
  __syncthreads();
  size_t row = (size_t)blockIdx.x * 256 + t;
  const float4* o4 = (const float4*)(ob + row * HDIM);
  float ov[32];
  #pragma unroll
  for (int i = 0; i < 8; ++i) {
    float4 o = o4[i];
    ov[i*4+0] = o.x; ov[i*4+1] = o.y; ov[i*4+2] = o.z; ov[i*4+3] = o.w;
  }
  float r[8];
  #pragma unroll
  for (int d = 0; d < 8; ++d) r[d] = boS[d];
  #pragma unroll
  for (int hd = 0; hd < 32; ++hd) {
    float o = ov[hd];
    #pragma unroll
    for (int d = 0; d < 8; ++d) r[d] += o * woS[hd*8 + d];
  }
  float* dst = out + row * DD;
  float4 r0 = { r[0], r[1], r[2], r[3] };
  float4 r1 = { r[4], r[5], r[6], r[7] };
  ((float4*)dst)[0] = r0;
  ((float4*)dst)[1] = r1;
}

extern "C" void kernel_launch(void* const* d_in, const int* in_sizes, int n_in,
                              void* d_out, int out_size, void* d_ws, size_t ws_size,
                              hipStream_t stream)
{
  const float* x  = (const float*)d_in[0];
  const int*   ei = (const int*)d_in[1];
  const float* Wq = (const float*)d_in[2];
  const float* bq = (const float*)d_in[3];
  const float* Wk = (const float*)d_in[4];
  const float* bk = (const float*)d_in[5];
  const float* Wv = (const float*)d_in[6];
  const float* bv = (const float*)d_in[7];
  const float* Wo = (const float*)d_in[8];
  const float* bo = (const float*)d_in[9];
  int E = in_sizes[1] / 2;

  char* ws = (char*)d_ws;
  u32*   mask = (u32*)(ws + 0);                 // 8 KB
  u32*   WtH  = (u32*)(ws + 8192);              // 24 KB (f16-packed W, transposed)
  float* bias = (float*)(ws + 8192 + 24576);    // 384 B
  __fp16* qh = (__fp16*)(ws + 65536);           // 4 MB each
  __fp16* kh = qh + (size_t)NROWS * HDIM;
  __fp16* vh = kh + (size_t)NROWS * HDIM;
  float* obuf  = (float*)(ws + 65536 + 3 * (size_t)NROWS * HDIM * 2);  // 8 MB

  prep_w_kernel<<<24, 256, 0, stream>>>(Wq, bq, Wk, bk, Wv, bv, mask, WtH, bias);
  prep_e_kernel<<<(E + 255) / 256, 256, 0, stream>>>(ei, E, mask);
  qkv_kernel<<<NROWS / 64, 256, 0, stream>>>(x, WtH, bias, qh, kh, vh);
  attn_kernel<<<NB * NH, 256, 0, stream>>>((const u32*)qh, (const u32*)kh,
                                           (const u32*)vh, mask, obuf);
  proj_kernel<<<NB, 256, 0, stream>>>(obuf, Wo, bo, (float*)d_out);
}

// Round 5
// 64.019 us; speedup vs baseline: 3.6513x; 1.4274x over previous
//
#include <hip/hip_runtime.h>

typedef unsigned int u32;
typedef unsigned short u16;
typedef __fp16 h2 __attribute__((ext_vector_type(2)));
typedef __fp16 h4 __attribute__((ext_vector_type(4)));
typedef float f32x16 __attribute__((ext_vector_type(16)));

#define NB 256
#define NNODE 256
#define FF 128
#define NH 4
#define DD 8
#define HDIM 32
#define NROWS (NB*NNODE)

__device__ __forceinline__ float dot2(h2 a, h2 b, float c) {
  return __builtin_amdgcn_fdot2(a, b, c, false);
}
__device__ __forceinline__ h2 bch2(u32 u) { return __builtin_bit_cast(h2, u); }
__device__ __forceinline__ h4 bch4(uint2 u) { return __builtin_bit_cast(h4, u); }
__device__ __forceinline__ u32 bcu(h2 v) { return __builtin_bit_cast(u32, v); }
__device__ __forceinline__ f32x16 fzero() {
  f32x16 z;
  #pragma unroll
  for (int r = 0; r < 16; ++r) z[r] = 0.f;
  return z;
}
__device__ __forceinline__ f32x16 mfma8(h4 a, h4 b, f32x16 c) {
  return __builtin_amdgcn_mfma_f32_32x32x8f16(a, b, c, 0, 0, 0);
}

// -------- prep_w: zero mask; WtH[c][k] f16-packed; bias f32; WoT packed -------
__global__ __launch_bounds__(256) void prep_w_kernel(
    const float* __restrict__ Wq, const float* __restrict__ bq,
    const float* __restrict__ Wk, const float* __restrict__ bk,
    const float* __restrict__ Wv, const float* __restrict__ bv,
    const float* __restrict__ Wo,
    u32* __restrict__ mask, u32* __restrict__ WtH, float* __restrict__ bias,
    u32* __restrict__ woT2)
{
  int g = blockIdx.x * 256 + threadIdx.x;
  if (g < 96 * 64) {                      // WtH[c][kp]: pack W[2kp][c],W[2kp+1][c]
    int c = g >> 6, f = (g & 63) * 2;
    const float* W = (c < 32) ? Wq : ((c < 64) ? Wk : Wv);
    int cc = c & 31;
    WtH[g] = bcu(__builtin_amdgcn_cvt_pkrtz(W[f*HDIM + cc], W[(f+1)*HDIM + cc]));
  }
  if (g < NNODE * 8) mask[g] = 0u;
  if (g < 96) {
    const float* bb = (g < 32) ? bq : ((g < 64) ? bk : bv);
    bias[g] = bb[g & 31];
  }
  if (g < 128) {                          // woT2[d][p] = pack Wo[2p][d],Wo[2p+1][d]
    int d = g >> 4, p = g & 15;
    woT2[g] = bcu(__builtin_amdgcn_cvt_pkrtz(Wo[(2*p)*DD + d], Wo[(2*p+1)*DD + d]));
  }
}

__global__ __launch_bounds__(256) void prep_e_kernel(
    const int* __restrict__ eidx, int E, u32* __restrict__ mask)
{
  int e = blockIdx.x * 256 + threadIdx.x;
  if (e < E) {
    int r = eidx[e], c = eidx[E + e];
    atomicOr(&mask[r*8 + (c >> 5)], 1u << (c & 31));
  }
}

// -------- QKV via MFMA: x[65536,128]f32 @ W[128,96] -> q,k,v f16 [65536,32] ----
// block 256 thr = 4 waves x 32 rows; per wave 3 col-tiles of 32, K in 16 steps
__global__ __launch_bounds__(256, 2) void qkv_kernel(
    const float* __restrict__ x, const u32* __restrict__ WtH,
    const float* __restrict__ bias,
    __fp16* __restrict__ qh, __fp16* __restrict__ kh, __fp16* __restrict__ vh)
{
  int t = threadIdx.x, lane = t & 63, w = t >> 6;
  int l31 = lane & 31, hi = lane >> 5;
  int row = blockIdx.x * 128 + w * 32 + l31;
  const float* xr = x + (size_t)row * FF + 4 * hi;

  f32x16 acc[3];
  #pragma unroll
  for (int ct = 0; ct < 3; ++ct) {
    float bb = bias[ct*32 + l31];
    #pragma unroll
    for (int r = 0; r < 16; ++r) acc[ct][r] = bb;
  }
  #pragma unroll
  for (int ks = 0; ks < 16; ++ks) {
    float4 xf = *(const float4*)(xr + ks*8);      // x[row][ks*8+4hi .. +3]
    h2 xl = __builtin_amdgcn_cvt_pkrtz(xf.x, xf.y);
    h2 xh = __builtin_amdgcn_cvt_pkrtz(xf.z, xf.w);
    h4 af = __builtin_shufflevector(xl, xh, 0, 1, 2, 3);
    #pragma unroll
    for (int ct = 0; ct < 3; ++ct) {
      h4 bf = bch4(*(const uint2*)(WtH + (size_t)(ct*32 + l31)*64 + ks*4 + 2*hi));
      acc[ct] = mfma8(af, bf, acc[ct]);
    }
  }
  #pragma unroll
  for (int ct = 0; ct < 3; ++ct) {
    __fp16* dst = (ct == 0) ? qh : ((ct == 1) ? kh : vh);
    #pragma unroll
    for (int r = 0; r < 16; ++r) {
      int rr = blockIdx.x*128 + w*32 + (r & 3) + 8*(r >> 2) + 4*hi;
      dst[(size_t)rr * HDIM + l31] = (__fp16)acc[ct][r];
    }
  }
}

// -------- attention, MFMA: per block one (b,h); T=K@Q^T, O^T=V^T@P^T -----------
__global__ __launch_bounds__(256, 4) void attn_kernel(
    const __fp16* __restrict__ qh, const __fp16* __restrict__ kh,
    const __fp16* __restrict__ vh, const u32* __restrict__ mask,
    __fp16* __restrict__ ob)
{
  __shared__ __fp16 kS[NNODE * 20];   // K head-slice, row stride 20 f16 (40B)
  __shared__ __fp16 vtS[32 * 260];    // V^T (+ones rows 8,12), row stride 520B
  __shared__ u32 mS[NNODE * 9];       // mask, row stride 9 u32
  int t = threadIdx.x;
  int lane = t & 63, w = t >> 6;
  int l31 = lane & 31, hi = lane >> 5;
  int b = blockIdx.x >> 2, h = blockIdx.x & 3;

  // zero V^T (incl. pad + unused rows)
  u32* vtU = (u32*)vtS;
  #pragma unroll
  for (int i = 0; i < 17; ++i) {
    int idx = t + i * 256;
    if (idx < 32 * 130) vtU[idx] = 0u;
  }
  // stage K rows
  const __fp16* kbase = kh + ((size_t)b * NNODE) * HDIM + h * DD;
  uint4 kr = *(const uint4*)(kbase + (size_t)t * HDIM);
  *(uint2*)&kS[t*20]     = make_uint2(kr.x, kr.y);
  *(uint2*)&kS[t*20 + 4] = make_uint2(kr.z, kr.w);
  // stage mask
  uint4 m0 = *(const uint4*)(mask + t*8);
  uint4 m1 = *(const uint4*)(mask + t*8 + 4);
  mS[t*9+0]=m0.x; mS[t*9+1]=m0.y; mS[t*9+2]=m0.z; mS[t*9+3]=m0.w;
  mS[t*9+4]=m1.x; mS[t*9+5]=m1.y; mS[t*9+6]=m1.z; mS[t*9+7]=m1.w;
  __syncthreads();
  // fill V^T + ones rows (8 and 12 -> row-sum l for both lane halves)
  const __fp16* vbase = vh + ((size_t)b * NNODE) * HDIM + h * DD;
  uint4 vr = *(const uint4*)(vbase + (size_t)t * HDIM);
  {
    h2 v0 = bch2(vr.x), v1 = bch2(vr.y), v2 = bch2(vr.z), v3 = bch2(vr.w);
    vtS[0*260 + t] = v0.x; vtS[1*260 + t] = v0.y;
    vtS[2*260 + t] = v1.x; vtS[3*260 + t] = v1.y;
    vtS[4*260 + t] = v2.x; vtS[5*260 + t] = v2.y;
    vtS[6*260 + t] = v3.x; vtS[7*260 + t] = v3.y;
    vtS[8*260 + t]  = (__fp16)1.0f;
    vtS[12*260 + t] = (__fp16)1.0f;
  }
  __syncthreads();

  // Q B-frags (2 q-tiles of 32 per wave), direct from global
  const __fp16* qbase = qh + ((size_t)b * NNODE) * HDIM + h * DD;
  h4 Qf[2];
  #pragma unroll
  for (int qt = 0; qt < 2; ++qt) {
    int qrow = w*64 + qt*32 + l31;
    Qf[qt] = bch4(*(const uint2*)(qbase + (size_t)qrow * HDIM + 4*hi));
  }
  // K A-frags for all 8 k-tiles
  h4 Kf[8];
  #pragma unroll
  for (int kt = 0; kt < 8; ++kt)
    Kf[kt] = bch4(*(const uint2*)&kS[(kt*32 + l31)*20 + 4*hi]);

  f32x16 accO[2] = { fzero(), fzero() };
  const float sc2 = 0.51006977f;      // (1/sqrt(8)) * log2(e)

  #pragma unroll
  for (int kt = 0; kt < 8; ++kt) {
    u32 phw[2][8];
    #pragma unroll
    for (int qt = 0; qt < 2; ++qt) {
      f32x16 T = mfma8(Kf[kt], Qf[qt], fzero());   // T[kr][q] = s(q, kt*32+kr)
      u32 mw = mS[(w*64 + qt*32 + l31)*9 + kt];
      u32 mwh = hi ? (mw >> 4) : mw;
      float p[16];
      #pragma unroll
      for (int r = 0; r < 16; ++r) {
        int bitpos = (r & 3) + 8*(r >> 2);         // kr - 4*hi
        float e = __builtin_fmaf(T[r], sc2, -8.0f); // anchor 2^-8: f16-safe range
        e = ((mwh >> bitpos) & 1u) ? e : -1e30f;
        p[r] = exp2f(e);
      }
      #pragma unroll
      for (int j = 0; j < 8; ++j)
        phw[qt][j] = bcu(__builtin_amdgcn_cvt_pkrtz(p[2*j], p[2*j+1]));
    }
    // PV: O^T += V^T[:, kt*32+kk*8 .. +7] @ P^T ; P B-frag = T regs 4kk..4kk+3
    #pragma unroll
    for (int kk = 0; kk < 4; ++kk) {
      h4 va = bch4(*(const uint2*)&vtS[l31*260 + kt*32 + kk*8 + 4*hi]);
      accO[0] = mfma8(va, bch4(make_uint2(phw[0][2*kk], phw[0][2*kk+1])), accO[0]);
      accO[1] = mfma8(va, bch4(make_uint2(phw[1][2*kk], phw[1][2*kk+1])), accO[1]);
    }
  }
  // epilogue: lane holds O^T col q=l31; regs 0..3 = d(4hi..4hi+3), reg 4 = l
  #pragma unroll
  for (int qt = 0; qt < 2; ++qt) {
    float inv = 1.0f / accO[qt][4];
    h2 o0 = __builtin_amdgcn_cvt_pkrtz(accO[qt][0]*inv, accO[qt][1]*inv);
    h2 o1 = __builtin_amdgcn_cvt_pkrtz(accO[qt][2]*inv, accO[qt][3]*inv);
    int qrow = w*64 + qt*32 + l31;
    *(uint2*)(ob + ((size_t)b * NNODE + qrow) * HDIM + h * DD + 4*hi)
        = make_uint2(bcu(o0), bcu(o1));
  }
}

// -------- output projection: obuf f16 [65536,32] @ Wo[32,8] + bo -> f32 --------
__global__ __launch_bounds__(256) void proj_kernel(
    const __fp16* __restrict__ ob, const u32* __restrict__ woT2,
    const float* __restrict__ bo, float* __restrict__ out)
{
  __shared__ u32 woS[128];
  __shared__ float boS[8];
  int t = threadIdx.x;
  if (t < 128) woS[t] = woT2[t];
  if (t < 8) boS[t] = bo[t];
  __syncthreads();
  size_t row = (size_t)blockIdx.x * 256 + t;
  const uint4* o4 = (const uint4*)(ob + row * HDIM);
  uint4 u0 = o4[0], u1 = o4[1], u2 = o4[2], u3 = o4[3];
  u32 ow[16] = { u0.x,u0.y,u0.z,u0.w, u1.x,u1.y,u1.z,u1.w,
                 u2.x,u2.y,u2.z,u2.w, u3.x,u3.y,u3.z,u3.w };
  float r[8];
  #pragma unroll
  for (int d = 0; d < 8; ++d) r[d] = boS[d];
  #pragma unroll
  for (int p = 0; p < 16; ++p) {
    h2 o2 = bch2(ow[p]);
    #pragma unroll
    for (int d = 0; d < 8; ++d) r[d] = dot2(o2, bch2(woS[d*16 + p]), r[d]);
  }
  float* dst = out + row * DD;
  float4 r0 = { r[0], r[1], r[2], r[3] };
  float4 r1 = { r[4], r[5], r[6], r[7] };
  ((float4*)dst)[0] = r0;
  ((float4*)dst)[1] = r1;
}

extern "C" void kernel_launch(void* const* d_in, const int* in_sizes, int n_in,
                              void* d_out, int out_size, void* d_ws, size_t ws_size,
                              hipStream_t stream)
{
  const float* x  = (const float*)d_in[0];
  const int*   ei = (const int*)d_in[1];
  const float* Wq = (const float*)d_in[2];
  const float* bq = (const float*)d_in[3];
  const float* Wk = (const float*)d_in[4];
  const float* bk = (const float*)d_in[5];
  const float* Wv = (const float*)d_in[6];
  const float* bv = (const float*)d_in[7];
  const float* Wo = (const float*)d_in[8];
  const float* bo = (const float*)d_in[9];
  int E = in_sizes[1] / 2;

  char* ws = (char*)d_ws;
  u32*   mask = (u32*)(ws + 0);                 // 8 KB
  u32*   WtH  = (u32*)(ws + 8192);              // 24 KB: W^T[c][k] f16-packed
  float* bias = (float*)(ws + 32768);           // 384 B
  u32*   woT2 = (u32*)(ws + 33280);             // 512 B
  __fp16* qh  = (__fp16*)(ws + 65536);          // 4 MB each
  __fp16* kh  = qh + (size_t)NROWS * HDIM;
  __fp16* vh  = kh + (size_t)NROWS * HDIM;
  __fp16* obuf = vh + (size_t)NROWS * HDIM;

  prep_w_kernel<<<24, 256, 0, stream>>>(Wq, bq, Wk, bk, Wv, bv, Wo,
                                        mask, WtH, bias, woT2);
  prep_e_kernel<<<(E + 255) / 256, 256, 0, stream>>>(ei, E, mask);
  qkv_kernel<<<NROWS / 128, 256, 0, stream>>>(x, WtH, bias, qh, kh, vh);
  attn_kernel<<<NB * NH, 256, 0, stream>>>(qh, kh, vh, mask, obuf);
  proj_kernel<<<NROWS / 256, 256, 0, stream>>>(obuf, woT2, bo, (float*)d_out);
}

// Round 6
// 54.332 us; speedup vs baseline: 4.3023x; 1.1783x over previous
//
#include <hip/hip_runtime.h>

typedef unsigned int u32;
typedef __fp16 h2 __attribute__((ext_vector_type(2)));
typedef __fp16 h4 __attribute__((ext_vector_type(4)));
typedef float f32x16 __attribute__((ext_vector_type(16)));

#define NB 256
#define NNODE 256
#define FF 128
#define NH 4
#define DD 8
#define HDIM 32
#define NROWS (NB*NNODE)

__device__ __forceinline__ float dot2(h2 a, h2 b, float c) {
  return __builtin_amdgcn_fdot2(a, b, c, false);
}
__device__ __forceinline__ h2 bch2(u32 u) { return __builtin_bit_cast(h2, u); }
__device__ __forceinline__ h4 bch4(uint2 u) { return __builtin_bit_cast(h4, u); }
__device__ __forceinline__ u32 bcu(h2 v) { return __builtin_bit_cast(u32, v); }
__device__ __forceinline__ f32x16 fzero() {
  f32x16 z;
  #pragma unroll
  for (int r = 0; r < 16; ++r) z[r] = 0.f;
  return z;
}
__device__ __forceinline__ f32x16 mfma8(h4 a, h4 b, f32x16 c) {
  return __builtin_amdgcn_mfma_f32_32x32x8f16(a, b, c, 0, 0, 0);
}

// -------- prep_w: zero mask; WtH[c][kp] f16-packed W^T; bias f32; WoT packed ----
__global__ __launch_bounds__(256) void prep_w_kernel(
    const float* __restrict__ Wq, const float* __restrict__ bq,
    const float* __restrict__ Wk, const float* __restrict__ bk,
    const float* __restrict__ Wv, const float* __restrict__ bv,
    const float* __restrict__ Wo,
    u32* __restrict__ mask, u32* __restrict__ WtH, float* __restrict__ bias,
    u32* __restrict__ woT2)
{
  int g = blockIdx.x * 256 + threadIdx.x;
  if (g < 96 * 64) {                      // WtH[c][kp]: pack W[2kp][c],W[2kp+1][c]
    int c = g >> 6, f = (g & 63) * 2;
    const float* W = (c < 32) ? Wq : ((c < 64) ? Wk : Wv);
    int cc = c & 31;
    WtH[g] = bcu(__builtin_amdgcn_cvt_pkrtz(W[f*HDIM + cc], W[(f+1)*HDIM + cc]));
  }
  if (g < NNODE * 8) mask[g] = 0u;
  if (g < 96) {
    const float* bb = (g < 32) ? bq : ((g < 64) ? bk : bv);
    bias[g] = bb[g & 31];
  }
  if (g < 128) {                          // woT2[d][p] = pack Wo[2p][d],Wo[2p+1][d]
    int d = g >> 4, p = g & 15;
    woT2[g] = bcu(__builtin_amdgcn_cvt_pkrtz(Wo[(2*p)*DD + d], Wo[(2*p+1)*DD + d]));
  }
}

__global__ __launch_bounds__(256) void prep_e_kernel(
    const int* __restrict__ eidx, int E, u32* __restrict__ mask)
{
  int e = blockIdx.x * 256 + threadIdx.x;
  if (e < E) {
    int r = eidx[e], c = eidx[E + e];
    atomicOr(&mask[r*8 + (c >> 5)], 1u << (c & 31));
  }
}

// -------- fused: per block one batch b; qkv (MFMA) -> attn (MFMA) -> proj -------
__global__ __launch_bounds__(512, 2) void fused_kernel(
    const float* __restrict__ x, const u32* __restrict__ WtH,
    const float* __restrict__ bias, const u32* __restrict__ mask,
    const u32* __restrict__ woT2, const float* __restrict__ bo,
    float* __restrict__ out)
{
  __shared__ __fp16 kS[NNODE * 36];    // k rows, stride 36 f16 (72 B) -> 2-way free
  __shared__ __fp16 vt32[32 * 260];    // V^T all 4 heads, stride 260 (520 B)
  __shared__ __fp16 oS[NNODE * 36];    // attn output rows
  __shared__ u32 woS[128];
  __shared__ float boS[8];

  int t = threadIdx.x;
  int lane = t & 63, w = t >> 6;       // 8 waves; wave w owns node tile w*32..+31
  int l31 = lane & 31, hi = lane >> 5;
  int b = blockIdx.x;
  int node = w * 32 + l31;

  if (t < 128) woS[t] = woT2[t];
  if (t < 8) boS[t] = bo[t];

  // ---- QKV phase: q^T = Wq^T @ x^T (C-frag == Q B-frags); k,v = x @ W ----
  const float* xr = x + ((size_t)b * NNODE + node) * FF + 4 * hi;
  f32x16 aq, ak, av;
  #pragma unroll
  for (int r = 0; r < 16; ++r) aq[r] = bias[(r & 3) + 8*(r >> 2) + 4*hi];
  {
    float bk_ = bias[32 + l31], bv_ = bias[64 + l31];
    #pragma unroll
    for (int r = 0; r < 16; ++r) { ak[r] = bk_; av[r] = bv_; }
  }
  #pragma unroll
  for (int ks = 0; ks < 16; ++ks) {
    float4 xf = *(const float4*)(xr + ks * 8);
    h2 xl = __builtin_amdgcn_cvt_pkrtz(xf.x, xf.y);
    h2 xh = __builtin_amdgcn_cvt_pkrtz(xf.z, xf.w);
    h4 xfrag = __builtin_shufflevector(xl, xh, 0, 1, 2, 3);
    h4 wq = bch4(*(const uint2*)(WtH + (size_t)l31 * 64 + ks*4 + 2*hi));
    h4 wk = bch4(*(const uint2*)(WtH + (size_t)(32 + l31) * 64 + ks*4 + 2*hi));
    h4 wv = bch4(*(const uint2*)(WtH + (size_t)(64 + l31) * 64 + ks*4 + 2*hi));
    aq = mfma8(wq, xfrag, aq);     // q^T: lane=q-col, reg 4h+j -> d=8h+4hi+j
    ak = mfma8(xfrag, wk, ak);     // k: lane=hd-col, reg -> node-row
    av = mfma8(xfrag, wv, av);     // v: same; scatter-write == transpose
  }
  #pragma unroll
  for (int r = 0; r < 16; ++r) {
    int nr = w*32 + (r & 3) + 8*(r >> 2) + 4*hi;
    kS[nr * 36 + l31] = (__fp16)ak[r];
    vt32[l31 * 260 + nr] = (__fp16)av[r];
  }
  // Q B-frags (all 4 heads) straight from aq regs
  h4 Qf[4];
  #pragma unroll
  for (int h = 0; h < 4; ++h) {
    h2 qa = __builtin_amdgcn_cvt_pkrtz(aq[4*h],     aq[4*h + 1]);
    h2 qb = __builtin_amdgcn_cvt_pkrtz(aq[4*h + 2], aq[4*h + 3]);
    Qf[h] = __builtin_shufflevector(qa, qb, 0, 1, 2, 3);
  }
  // adjacency words for this lane's q-row (shared across heads)
  uint4 m0 = *(const uint4*)(mask + node * 8);
  uint4 m1 = *(const uint4*)(mask + node * 8 + 4);
  u32 mw8[8] = { m0.x, m0.y, m0.z, m0.w, m1.x, m1.y, m1.z, m1.w };
  #pragma unroll
  for (int i = 0; i < 8; ++i) mw8[i] = hi ? (mw8[i] >> 4) : mw8[i];

  __syncthreads();

  // ---- attention per head: T = K @ Q^T; P^T C-frag == PV B-frag; O^T = V^T @ P^T
  const float sc2 = 0.51006977f;       // (1/sqrt(8)) * log2(e)
  #pragma unroll
  for (int h = 0; h < 4; ++h) {
    f32x16 accO = fzero();
    float lp = 0.f;
    #pragma unroll
    for (int kt = 0; kt < 8; ++kt) {
      h4 Kf = bch4(*(const uint2*)&kS[(kt*32 + l31) * 36 + h*8 + 4*hi]);
      f32x16 T = mfma8(Kf, Qf[h], fzero());   // T[kr][q=l31]
      u32 mwh = mw8[kt];
      u32 phw[8];
      #pragma unroll
      for (int j = 0; j < 8; ++j) {
        int r0 = 2*j, r1 = 2*j + 1;
        float e0 = __builtin_fmaf(T[r0], sc2, -8.0f);   // anchor 2^-8 (f16-safe)
        float e1 = __builtin_fmaf(T[r1], sc2, -8.0f);
        int bp0 = (r0 & 3) + 8*(r0 >> 2), bp1 = (r1 & 3) + 8*(r1 >> 2);
        e0 = ((mwh >> bp0) & 1u) ? e0 : -1e30f;
        e1 = ((mwh >> bp1) & 1u) ? e1 : -1e30f;
        float p0 = exp2f(e0), p1 = exp2f(e1);
        lp += p0; lp += p1;
        phw[j] = bcu(__builtin_amdgcn_cvt_pkrtz(p0, p1));
      }
      #pragma unroll
      for (int kk = 0; kk < 4; ++kk) {
        h4 va = bch4(*(const uint2*)&vt32[l31 * 260 + kt*32 + kk*8 + 4*hi]);
        accO = mfma8(va, bch4(make_uint2(phw[2*kk], phw[2*kk + 1])), accO);
      }
    }
    float lq = lp + __shfl_xor(lp, 32);
    float inv = 1.0f / lq;
    h2 o0 = __builtin_amdgcn_cvt_pkrtz(accO[4*h] * inv,     accO[4*h + 1] * inv);
    h2 o1 = __builtin_amdgcn_cvt_pkrtz(accO[4*h + 2] * inv, accO[4*h + 3] * inv);
    *(uint2*)&oS[node * 36 + 8*h + 4*hi] = make_uint2(bcu(o0), bcu(o1));
  }
  __syncthreads();

  // ---- proj: out[row] = oS[row] @ Wo + bo; thread pair per row ----
  int row = t >> 1, d4 = (t & 1) * 4;
  float r4[4] = { boS[d4], boS[d4+1], boS[d4+2], boS[d4+3] };
  #pragma unroll
  for (int p = 0; p < 16; ++p) {
    h2 o2 = bch2(*(const u32*)&oS[row * 36 + 2*p]);
    #pragma unroll
    for (int d = 0; d < 4; ++d)
      r4[d] = dot2(o2, bch2(woS[(d4 + d) * 16 + p]), r4[d]);
  }
  float4 o = { r4[0], r4[1], r4[2], r4[3] };
  *(float4*)(out + ((size_t)b * NNODE + row) * DD + d4) = o;
}

extern "C" void kernel_launch(void* const* d_in, const int* in_sizes, int n_in,
                              void* d_out, int out_size, void* d_ws, size_t ws_size,
                              hipStream_t stream)
{
  const float* x  = (const float*)d_in[0];
  const int*   ei = (const int*)d_in[1];
  const float* Wq = (const float*)d_in[2];
  const float* bq = (const float*)d_in[3];
  const float* Wk = (const float*)d_in[4];
  const float* bk = (const float*)d_in[5];
  const float* Wv = (const float*)d_in[6];
  const float* bv = (const float*)d_in[7];
  const float* Wo = (const float*)d_in[8];
  const float* bo = (const float*)d_in[9];
  int E = in_sizes[1] / 2;

  char* ws = (char*)d_ws;
  u32*   mask = (u32*)(ws + 0);                 // 8 KB
  u32*   WtH  = (u32*)(ws + 8192);              // 24 KB: W^T[c][kp] f16-packed
  float* bias = (float*)(ws + 32768);           // 384 B
  u32*   woT2 = (u32*)(ws + 33280);             // 512 B

  prep_w_kernel<<<24, 256, 0, stream>>>(Wq, bq, Wk, bk, Wv, bv, Wo,
                                        mask, WtH, bias, woT2);
  prep_e_kernel<<<(E + 255) / 256, 256, 0, stream>>>(ei, E, mask);
  fused_kernel<<<NB, 512, 0, stream>>>(x, WtH, bias, mask, woT2, bo,
                                       (float*)d_out);
}

// Round 7
// 43.199 us; speedup vs baseline: 5.4110x; 1.2577x over previous
//
#include <hip/hip_runtime.h>

typedef unsigned int u32;
typedef __fp16 h2 __attribute__((ext_vector_type(2)));
typedef __fp16 h4 __attribute__((ext_vector_type(4)));
typedef float f32x16 __attribute__((ext_vector_type(16)));

#define NB 256
#define NNODE 256
#define FF 128
#define NH 4
#define DD 8
#define HDIM 32
#define NROWS (NB*NNODE)

__device__ __forceinline__ float dot2(h2 a, h2 b, float c) {
  return __builtin_amdgcn_fdot2(a, b, c, false);
}
__device__ __forceinline__ h2 bch2(u32 u) { return __builtin_bit_cast(h2, u); }
__device__ __forceinline__ h4 bch4(uint2 u) { return __builtin_bit_cast(h4, u); }
__device__ __forceinline__ u32 bcu(h2 v) { return __builtin_bit_cast(u32, v); }
__device__ __forceinline__ f32x16 fzero() {
  f32x16 z;
  #pragma unroll
  for (int r = 0; r < 16; ++r) z[r] = 0.f;
  return z;
}
__device__ __forceinline__ f32x16 mfma8(h4 a, h4 b, f32x16 c) {
  return __builtin_amdgcn_mfma_f32_32x32x8f16(a, b, c, 0, 0, 0);
}

// -------- prep_w: zero mask; WtH[c][kp] f16-packed W^T; bias f32; WoT packed ----
__global__ __launch_bounds__(256) void prep_w_kernel(
    const float* __restrict__ Wq, const float* __restrict__ bq,
    const float* __restrict__ Wk, const float* __restrict__ bk,
    const float* __restrict__ Wv, const float* __restrict__ bv,
    const float* __restrict__ Wo,
    u32* __restrict__ mask, u32* __restrict__ WtH, float* __restrict__ bias,
    u32* __restrict__ woT2)
{
  int g = blockIdx.x * 256 + threadIdx.x;
  if (g < 96 * 64) {                      // WtH[c][kp]: pack W[2kp][c],W[2kp+1][c]
    int c = g >> 6, f = (g & 63) * 2;
    const float* W = (c < 32) ? Wq : ((c < 64) ? Wk : Wv);
    int cc = c & 31;
    WtH[g] = bcu(__builtin_amdgcn_cvt_pkrtz(W[f*HDIM + cc], W[(f+1)*HDIM + cc]));
  }
  if (g < NNODE * 8) mask[g] = 0u;
  if (g < 96) {
    const float* bb = (g < 32) ? bq : ((g < 64) ? bk : bv);
    bias[g] = bb[g & 31];
  }
  if (g < 128) {                          // woT2[d][p] = pack Wo[2p][d],Wo[2p+1][d]
    int d = g >> 4, p = g & 15;
    woT2[g] = bcu(__builtin_amdgcn_cvt_pkrtz(Wo[(2*p)*DD + d], Wo[(2*p+1)*DD + d]));
  }
}

__global__ __launch_bounds__(256) void prep_e_kernel(
    const int* __restrict__ eidx, int E, u32* __restrict__ mask)
{
  int e = blockIdx.x * 256 + threadIdx.x;
  if (e < E) {
    int r = eidx[e], c = eidx[E + e];
    atomicOr(&mask[r*8 + (c >> 5)], 1u << (c & 31));
  }
}

// -------- fused: 2 blocks per batch (4 waves each); qkv -> attn -> proj --------
// Block (b, half): q/attn/proj for rows half*128..+127; k,v for all 256 nodes.
__global__ __launch_bounds__(256, 2) void fused_kernel(
    const float* __restrict__ x, const u32* __restrict__ WtH,
    const float* __restrict__ bias, const u32* __restrict__ mask,
    const u32* __restrict__ woT2, const float* __restrict__ bo,
    float* __restrict__ out)
{
  __shared__ u32 wLds[96 * 66];        // 25.3 KB; stride 66 -> banks spread
  __shared__ __fp16 kS[NNODE * 36];    // 18 KB, stride 36 f16
  __shared__ __fp16 vt32[32 * 260];    // 16.3 KB, V^T all heads, stride 260
  __shared__ __fp16 oS[128 * 36];      // 9 KB, own q-rows
  __shared__ u32 woS[128];
  __shared__ float boS[8];

  int t = threadIdx.x, lane = t & 63, w = t >> 6;   // 4 waves
  int l31 = lane & 31, hi = lane >> 5;
  int b = blockIdx.x >> 1, half = blockIdx.x & 1;

  // stage W (coalesced global read, strided LDS write)
  for (int g = t; g < 96 * 64; g += 256)
    wLds[(g >> 6) * 66 + (g & 63)] = WtH[g];
  if (t < 128) woS[t] = woT2[t];
  if (t < 8) boS[t] = bo[t];

  // ---- QKV phase ----
  f32x16 aq;
  #pragma unroll
  for (int r = 0; r < 16; ++r) aq[r] = bias[(r & 3) + 8*(r >> 2) + 4*hi];
  float bk_ = bias[32 + l31], bv_ = bias[64 + l31];
  __syncthreads();

  #pragma unroll
  for (int i = 0; i < 2; ++i) {
    int nt = w + 4 * i;                 // node tile handled by this wave
    const float* xr = x + ((size_t)b * NNODE + nt*32 + l31) * FF + 4 * hi;
    f32x16 ak, av;
    #pragma unroll
    for (int r = 0; r < 16; ++r) { ak[r] = bk_; av[r] = bv_; }
    bool own = (i == half);             // this tile holds our q-rows
    #pragma unroll
    for (int ks = 0; ks < 16; ++ks) {
      float4 xf = *(const float4*)(xr + ks * 8);
      h2 xl = __builtin_amdgcn_cvt_pkrtz(xf.x, xf.y);
      h2 xh = __builtin_amdgcn_cvt_pkrtz(xf.z, xf.w);
      h4 xfrag = __builtin_shufflevector(xl, xh, 0, 1, 2, 3);
      h4 wk = bch4(*(const uint2*)&wLds[(32 + l31)*66 + ks*4 + 2*hi]);
      h4 wv = bch4(*(const uint2*)&wLds[(64 + l31)*66 + ks*4 + 2*hi]);
      ak = mfma8(xfrag, wk, ak);
      av = mfma8(xfrag, wv, av);
      if (own) {
        h4 wq = bch4(*(const uint2*)&wLds[l31*66 + ks*4 + 2*hi]);
        aq = mfma8(wq, xfrag, aq);      // q^T: lane=q-col(node), reg=d
      }
    }
    #pragma unroll
    for (int r = 0; r < 16; ++r) {
      int nr = nt*32 + (r & 3) + 8*(r >> 2) + 4*hi;
      kS[nr * 36 + l31] = (__fp16)ak[r];
      vt32[l31 * 260 + nr] = (__fp16)av[r];
    }
  }

  // Q B-frags from aq regs; adjacency words for own q-row
  h4 Qf[4];
  #pragma unroll
  for (int h = 0; h < 4; ++h) {
    h2 qa = __builtin_amdgcn_cvt_pkrtz(aq[4*h],     aq[4*h + 1]);
    h2 qb = __builtin_amdgcn_cvt_pkrtz(aq[4*h + 2], aq[4*h + 3]);
    Qf[h] = __builtin_shufflevector(qa, qb, 0, 1, 2, 3);
  }
  int node = half*128 + w*32 + l31;     // own q-row (== mask row)
  uint4 m0 = *(const uint4*)(mask + node * 8);
  uint4 m1 = *(const uint4*)(mask + node * 8 + 4);
  u32 mw8[8] = { m0.x, m0.y, m0.z, m0.w, m1.x, m1.y, m1.z, m1.w };
  #pragma unroll
  for (int i = 0; i < 8; ++i) mw8[i] = hi ? (mw8[i] >> 4) : mw8[i];

  __syncthreads();

  // ---- attention: head pairs interleaved for ILP ----
  const float sc2 = 0.51006977f;        // (1/sqrt(8)) * log2(e)
  int lr = w*32 + l31;                  // local q-row 0..127
  #pragma unroll
  for (int hp = 0; hp < 2; ++hp) {
    int h0 = 2*hp, h1 = 2*hp + 1;
    f32x16 accO0 = fzero(), accO1 = fzero();
    float lp0 = 0.f, lp1 = 0.f;
    #pragma unroll
    for (int kt = 0; kt < 8; ++kt) {
      h4 Kf0 = bch4(*(const uint2*)&kS[(kt*32 + l31)*36 + h0*8 + 4*hi]);
      h4 Kf1 = bch4(*(const uint2*)&kS[(kt*32 + l31)*36 + h1*8 + 4*hi]);
      f32x16 T0 = mfma8(Kf0, Qf[h0], fzero());   // T[kr][q=l31]
      f32x16 T1 = mfma8(Kf1, Qf[h1], fzero());
      u32 mwh = mw8[kt];
      u32 phw0[8], phw1[8];
      #pragma unroll
      for (int j = 0; j < 8; ++j) {
        int r0 = 2*j, r1 = 2*j + 1;
        int bp0 = (r0 & 3) + 8*(r0 >> 2), bp1 = (r1 & 3) + 8*(r1 >> 2);
        bool ma = (mwh >> bp0) & 1u, mb = (mwh >> bp1) & 1u;
        float e00 = ma ? __builtin_fmaf(T0[r0], sc2, -8.0f) : -1e30f;
        float e01 = mb ? __builtin_fmaf(T0[r1], sc2, -8.0f) : -1e30f;
        float e10 = ma ? __builtin_fmaf(T1[r0], sc2, -8.0f) : -1e30f;
        float e11 = mb ? __builtin_fmaf(T1[r1], sc2, -8.0f) : -1e30f;
        float p00 = __builtin_amdgcn_exp2f(e00);
        float p01 = __builtin_amdgcn_exp2f(e01);
        float p10 = __builtin_amdgcn_exp2f(e10);
        float p11 = __builtin_amdgcn_exp2f(e11);
        lp0 += p00 + p01; lp1 += p10 + p11;
        phw0[j] = bcu(__builtin_amdgcn_cvt_pkrtz(p00, p01));
        phw1[j] = bcu(__builtin_amdgcn_cvt_pkrtz(p10, p11));
      }
      #pragma unroll
      for (int kk = 0; kk < 4; ++kk) {
        h4 va = bch4(*(const uint2*)&vt32[l31*260 + kt*32 + kk*8 + 4*hi]);
        accO0 = mfma8(va, bch4(make_uint2(phw0[2*kk], phw0[2*kk+1])), accO0);
        accO1 = mfma8(va, bch4(make_uint2(phw1[2*kk], phw1[2*kk+1])), accO1);
      }
    }
    float lq0 = lp0 + __shfl_xor(lp0, 32);
    float lq1 = lp1 + __shfl_xor(lp1, 32);
    float inv0 = 1.0f / lq0, inv1 = 1.0f / lq1;
    h2 a0 = __builtin_amdgcn_cvt_pkrtz(accO0[4*h0]*inv0,   accO0[4*h0+1]*inv0);
    h2 a1 = __builtin_amdgcn_cvt_pkrtz(accO0[4*h0+2]*inv0, accO0[4*h0+3]*inv0);
    *(uint2*)&oS[lr*36 + 8*h0 + 4*hi] = make_uint2(bcu(a0), bcu(a1));
    h2 c0 = __builtin_amdgcn_cvt_pkrtz(accO1[4*h1]*inv1,   accO1[4*h1+1]*inv1);
    h2 c1 = __builtin_amdgcn_cvt_pkrtz(accO1[4*h1+2]*inv1, accO1[4*h1+3]*inv1);
    *(uint2*)&oS[lr*36 + 8*h1 + 4*hi] = make_uint2(bcu(c0), bcu(c1));
  }
  __syncthreads();

  // ---- proj: 2 threads per row; out = oS @ Wo + bo ----
  int pr = t >> 1, d4 = (t & 1) * 4;
  float r4[4] = { boS[d4], boS[d4+1], boS[d4+2], boS[d4+3] };
  #pragma unroll
  for (int p = 0; p < 16; ++p) {
    h2 o2 = bch2(*(const u32*)&oS[pr*36 + 2*p]);
    #pragma unroll
    for (int d = 0; d < 4; ++d)
      r4[d] = dot2(o2, bch2(woS[(d4 + d)*16 + p]), r4[d]);
  }
  float4 o = { r4[0], r4[1], r4[2], r4[3] };
  *(float4*)(out + ((size_t)b * NNODE + half*128 + pr) * DD + d4) = o;
}

extern "C" void kernel_launch(void* const* d_in, const int* in_sizes, int n_in,
                              void* d_out, int out_size, void* d_ws, size_t ws_size,
                              hipStream_t stream)
{
  const float* x  = (const float*)d_in[0];
  const int*   ei = (const int*)d_in[1];
  const float* Wq = (const float*)d_in[2];
  const float* bq = (const float*)d_in[3];
  const float* Wk = (const float*)d_in[4];
  const float* bk = (const float*)d_in[5];
  const float* Wv = (const float*)d_in[6];
  const float* bv = (const float*)d_in[7];
  const float* Wo = (const float*)d_in[8];
  const float* bo = (const float*)d_in[9];
  int E = in_sizes[1] / 2;

  char* ws = (char*)d_ws;
  u32*   mask = (u32*)(ws + 0);                 // 8 KB
  u32*   WtH  = (u32*)(ws + 8192);              // 24 KB: W^T[c][kp] f16-packed
  float* bias = (float*)(ws + 32768);           // 384 B
  u32*   woT2 = (u32*)(ws + 33280);             // 512 B

  prep_w_kernel<<<24, 256, 0, stream>>>(Wq, bq, Wk, bk, Wv, bv, Wo,
                                        mask, WtH, bias, woT2);
  prep_e_kernel<<<(E + 255) / 256, 256, 0, stream>>>(ei, E, mask);
  fused_kernel<<<NB * 2, 256, 0, stream>>>(x, WtH, bias, mask, woT2, bo,
                                           (float*)d_out);
}